// Round 6
// baseline (133.374 us; speedup 1.0000x reference)
//
#include <hip/hip_runtime.h>
#include <hip/hip_bf16.h>

typedef __attribute__((ext_vector_type(8))) short bfx8;
typedef __attribute__((ext_vector_type(4))) short bfx4;
typedef __attribute__((ext_vector_type(4))) float fx4;

static __device__ __forceinline__ short f2bf(float f) {
  union { float f; unsigned u; } v; v.f = f;
  unsigned r = v.u + 0x7fffu + ((v.u >> 16) & 1u);
  return (short)(r >> 16);
}

static __device__ __forceinline__ void gld16(const void* g, void* l) {
  __builtin_amdgcn_global_load_lds(
      (const __attribute__((address_space(1))) void*)g,
      (__attribute__((address_space(3))) void*)l, 16, 0, 0);
}

constexpr int Bz = 8, Sq = 512, Em = 1024, Hn = 16, Dh = 64;
constexpr int Mrows = Bz * Sq;             // 4096
constexpr size_t NE = (size_t)Mrows * Em;  // 4,194,304
constexpr size_t WE = (size_t)Em * Em;     // 1,048,576

// ---------------- f32 -> bf16 pre-convert (memory-bound, exact flat grid) ----------------
__global__ __launch_bounds__(256) void convert_kernel(
    const float* __restrict__ q, const float* __restrict__ k,
    const float* __restrict__ v,
    const float* __restrict__ Wq, const float* __restrict__ Wk,
    const float* __restrict__ Wv, const float* __restrict__ Wo,
    short* __restrict__ qx, short* __restrict__ kx, short* __restrict__ vx,
    short* __restrict__ wqb, short* __restrict__ wkb,
    short* __restrict__ wvb, short* __restrict__ wob)
{
  const size_t c = (size_t)blockIdx.x * 256 + threadIdx.x;  // vec8 chunk id
  constexpr size_t CI = NE / 8;   // 524288
  constexpr size_t CW = WE / 8;   // 131072
  const float* src; short* dst; size_t off;
  if (c < 3 * CI) {
    const int sgi = (int)(c / CI);
    src = sgi == 0 ? q : sgi == 1 ? k : v;
    dst = sgi == 0 ? qx : sgi == 1 ? kx : vx;
    off = (c - (size_t)sgi * CI) * 8;
  } else {
    const size_t w = c - 3 * CI;
    const int sgi = (int)(w / CW);
    src = sgi == 0 ? Wq : sgi == 1 ? Wk : sgi == 2 ? Wv : Wo;
    dst = sgi == 0 ? wqb : sgi == 1 ? wkb : sgi == 2 ? wvb : wob;
    off = (w - (size_t)sgi * CW) * 8;
  }
  fx4 a = *(const fx4*)(src + off);
  fx4 b = *(const fx4*)(src + off + 4);
  bfx8 o = { f2bf(a[0]), f2bf(a[1]), f2bf(a[2]), f2bf(a[3]),
             f2bf(b[0]), f2bf(b[1]), f2bf(b[2]), f2bf(b[3]) };
  *(bfx8*)(dst + off) = o;
}

// ---------------- bf16 GEMM, C^T orientation, 2-phase double-buffered ----------------
// LDS: dbuf = {A0,B0,A1,B1} 4x4096 elems (32KB); epilogue reuses SM as 128x136
// C-tile (34.8KB total union). Prefetch tile t+1 issued before compute of t;
// single __syncthreads per K-step (vmcnt drain overlapped with compute).
constexpr int LDP = 136;

__global__ __launch_bounds__(256) void gemm_qkv_bf16(
    const short* __restrict__ qx, const short* __restrict__ kx,
    const short* __restrict__ vx,
    const short* __restrict__ Wqb, const short* __restrict__ Wkb,
    const short* __restrict__ Wvb,
    const float* __restrict__ bq, const float* __restrict__ bk,
    const float* __restrict__ bv,
    const float* __restrict__ pos,
    short* __restrict__ qb, short* __restrict__ kb, short* __restrict__ vb)
{
  __shared__ short SM[128 * LDP];

  const int z = blockIdx.z;
  const short* X = (z == 0) ? qx : (z == 1) ? kx : vx;
  const short* W = (z == 0) ? Wqb : (z == 1) ? Wkb : Wvb;
  const float* bias = (z == 0) ? bq : (z == 1) ? bk : bv;
  short* dst = (z == 0) ? qb : (z == 1) ? kb : vb;

  const int m0 = blockIdx.x * 128;   // over Mrows (fast axis -> XCD locality)
  const int n0 = blockIdx.y * 128;   // over Em
  const int t = threadIdx.x, lane = t & 63, wave = t >> 6;
  const int wr = wave >> 1, wc = wave & 1;
  const int fr = lane & 15, fq = lane >> 4;

  const int r0 = t >> 2, o0 = (t & 3) * 8;
  const int r1 = r0 + 64;
  const short* gW0 = W + (size_t)(n0 + r0) * Em + o0;
  const short* gW1 = W + (size_t)(n0 + r1) * Em + o0;
  const short* gX0 = X + (size_t)(m0 + r0) * Em + o0;
  const short* gX1 = X + (size_t)(m0 + r1) * Em + o0;

  fx4 acc[4][4] = {};

  auto stage = [&](int kk, short* Ab, short* Bb) {
    gld16(gW0 + kk, Ab + wave * 512);
    gld16(gW1 + kk, Ab + 2048 + wave * 512);
    gld16(gX0 + kk, Bb + wave * 512);
    gld16(gX1 + kk, Bb + 2048 + wave * 512);
  };
  auto compute = [&](const short* Asb, const short* Bsb) {
    bfx8 af[4], bf[4];
#pragma unroll
    for (int u = 0; u < 4; ++u)
      af[u] = *(const bfx8*)&Asb[(wr * 64 + u * 16 + fr) * 32 + fq * 8];
#pragma unroll
    for (int v = 0; v < 4; ++v)
      bf[v] = *(const bfx8*)&Bsb[(wc * 64 + v * 16 + fr) * 32 + fq * 8];
#pragma unroll
    for (int u = 0; u < 4; ++u)
#pragma unroll
      for (int v = 0; v < 4; ++v)
        acc[u][v] = __builtin_amdgcn_mfma_f32_16x16x32_bf16(af[u], bf[v], acc[u][v], 0, 0, 0);
  };

  short* A0 = SM;
  short* B0 = SM + 4096;
  short* A1 = SM + 8192;
  short* B1 = SM + 12288;

  stage(0, A0, B0);
  __syncthreads();
  for (int k0 = 0; k0 < Em; k0 += 64) {
    // phase A: prefetch k0+32 -> buf1, compute buf0
    stage(k0 + 32, A1, B1);
    compute(A0, B0);
    __syncthreads();
    // phase B: prefetch k0+64 -> buf0 (if any), compute buf1
    if (k0 + 64 < Em) stage(k0 + 64, A0, B0);
    compute(A1, B1);
    __syncthreads();
  }

  // ---- epilogue: +bias+pe, bounce through LDS, coalesced bfx8 stores ----
  const int rr = t >> 4, jj = t & 15;
  const int b = m0 >> 9;
  if (z < 2) {
    // C-tile [m][nn], readback rows m -> [B,H,S,Dh] (contiguous d)
#pragma unroll
    for (int u = 0; u < 4; ++u) {
      const int nn = wr * 64 + u * 16 + fq * 4;
      const int nng = n0 + nn;
      const fx4 bb = *(const fx4*)&bias[nng];
#pragma unroll
      for (int v = 0; v < 4; ++v) {
        const int m = wc * 64 + v * 16 + fr;
        const int s = (m0 + m) & (Sq - 1);
        const fx4 pe = *(const fx4*)&pos[(size_t)s * Em + nng];
        const fx4 a = acc[u][v];
        bfx4 o = { f2bf(a[0] + bb[0] + pe[0]), f2bf(a[1] + bb[1] + pe[1]),
                   f2bf(a[2] + bb[2] + pe[2]), f2bf(a[3] + bb[3] + pe[3]) };
        *(bfx4*)&SM[m * LDP + nn] = o;
      }
    }
    __syncthreads();
#pragma unroll
    for (int it = 0; it < 8; ++it) {
      const int m = it * 16 + rr;
      const int s = (m0 + m) & (Sq - 1);
      bfx8 val = *(const bfx8*)&SM[m * LDP + jj * 8];
      const int nng = n0 + jj * 8;
      const int h = nng >> 6, d = nng & 63;
      *(bfx8*)&dst[(((size_t)b * Hn + h) * Sq + s) * Dh + d] = val;
    }
  } else {
    // C-tile [nn][m^swz]; readback rows nn -> V^T [B,H,Dh,S] (contiguous s)
#pragma unroll
    for (int u = 0; u < 4; ++u) {
      const int nnb = wr * 64 + u * 16 + fq * 4;
      const int nng = n0 + nnb;
      const fx4 bb = *(const fx4*)&bias[nng];
#pragma unroll
      for (int v = 0; v < 4; ++v) {
        const int m = wc * 64 + v * 16 + fr;
        const int s = (m0 + m) & (Sq - 1);
        const fx4 pe = *(const fx4*)&pos[(size_t)s * Em + nng];
        const fx4 a = acc[u][v];
#pragma unroll
        for (int i = 0; i < 4; ++i) {
          const int row = nnb + i;
          SM[row * LDP + (m ^ ((row & 12) << 2))] = f2bf(a[i] + bb[i] + pe[i]);
        }
      }
    }
    __syncthreads();
    const int s0 = m0 & (Sq - 1);
#pragma unroll
    for (int it = 0; it < 8; ++it) {
      const int row = it * 16 + rr;
      bfx8 val = *(const bfx8*)&SM[row * LDP + ((jj * 8) ^ ((row & 12) << 2))];
      const int nng = n0 + row;
      const int h = nng >> 6, d = nng & 63;
      *(bfx8*)&dst[(((size_t)b * Hn + h) * Dh + d) * Sq + s0 + jj * 8] = val;
    }
  }
}

// output projection: out = wv @ Wo^T + bo  (f32 out, vector stores)
__global__ __launch_bounds__(256) void gemm_out_bf16(
    const short* __restrict__ wv, const short* __restrict__ Wob,
    const float* __restrict__ bo, float* __restrict__ out)
{
  __shared__ short SM[4 * 4096];

  const int m0 = blockIdx.x * 128;
  const int n0 = blockIdx.y * 128;
  const int t = threadIdx.x, lane = t & 63, wave = t >> 6;
  const int wr = wave >> 1, wc = wave & 1;
  const int fr = lane & 15, fq = lane >> 4;

  const int r0 = t >> 2, o0 = (t & 3) * 8;
  const int r1 = r0 + 64;
  const short* gW0 = Wob + (size_t)(n0 + r0) * Em + o0;
  const short* gW1 = Wob + (size_t)(n0 + r1) * Em + o0;
  const short* gX0 = wv + (size_t)(m0 + r0) * Em + o0;
  const short* gX1 = wv + (size_t)(m0 + r1) * Em + o0;

  fx4 acc[4][4] = {};

  auto stage = [&](int kk, short* Ab, short* Bb) {
    gld16(gW0 + kk, Ab + wave * 512);
    gld16(gW1 + kk, Ab + 2048 + wave * 512);
    gld16(gX0 + kk, Bb + wave * 512);
    gld16(gX1 + kk, Bb + 2048 + wave * 512);
  };
  auto compute = [&](const short* Asb, const short* Bsb) {
    bfx8 af[4], bf[4];
#pragma unroll
    for (int u = 0; u < 4; ++u)
      af[u] = *(const bfx8*)&Asb[(wr * 64 + u * 16 + fr) * 32 + fq * 8];
#pragma unroll
    for (int v = 0; v < 4; ++v)
      bf[v] = *(const bfx8*)&Bsb[(wc * 64 + v * 16 + fr) * 32 + fq * 8];
#pragma unroll
    for (int u = 0; u < 4; ++u)
#pragma unroll
      for (int v = 0; v < 4; ++v)
        acc[u][v] = __builtin_amdgcn_mfma_f32_16x16x32_bf16(af[u], bf[v], acc[u][v], 0, 0, 0);
  };

  short* A0 = SM;
  short* B0 = SM + 4096;
  short* A1 = SM + 8192;
  short* B1 = SM + 12288;

  stage(0, A0, B0);
  __syncthreads();
  for (int k0 = 0; k0 < Em; k0 += 64) {
    stage(k0 + 32, A1, B1);
    compute(A0, B0);
    __syncthreads();
    if (k0 + 64 < Em) stage(k0 + 64, A0, B0);
    compute(A1, B1);
    __syncthreads();
  }

#pragma unroll
  for (int u = 0; u < 4; ++u) {
    const int nn = n0 + wr * 64 + u * 16 + fq * 4;
    const fx4 bb = *(const fx4*)&bo[nn];
#pragma unroll
    for (int v = 0; v < 4; ++v) {
      const int m = m0 + wc * 64 + v * 16 + fr;
      fx4 val = acc[u][v];
      val[0] += bb[0]; val[1] += bb[1]; val[2] += bb[2]; val[3] += bb[3];
      *(fx4*)&out[(size_t)m * Em + nn] = val;
    }
  }
}

// ---------------- Attention (unchanged from R5) ----------------
constexpr int KVB = 64, LDK = 72;

__global__ __launch_bounds__(256) void attn_kernel(
    const short* __restrict__ qb, const short* __restrict__ kb,
    const short* __restrict__ vb, short* __restrict__ wv)
{
  __shared__ short Ks[KVB * LDK];
  __shared__ short Vt[Dh * LDK];
  __shared__ short Ps[4][16 * LDK];

  const int bh = blockIdx.x;
  const int qt = blockIdx.y;
  const int t = threadIdx.x, lane = t & 63, wave = t >> 6;
  const int fr = lane & 15, fq = lane >> 4;

  const size_t base = (size_t)bh * Sq * Dh;
  const int q0 = qt * 64 + wave * 16;

  bfx8 qf[2];
  {
    const short* qp = qb + base + (size_t)(q0 + fr) * Dh;
    qf[0] = *(const bfx8*)(qp + fq * 8);
    qf[1] = *(const bfx8*)(qp + 32 + fq * 8);
  }

  float mrow[4] = { -1e30f, -1e30f, -1e30f, -1e30f };
  float lrow[4] = { 0.f, 0.f, 0.f, 0.f };
  fx4 oacc[4] = {};

  const int kr = t >> 2, kc = (t & 3) * 16;

  for (int kv0 = 0; kv0 < Sq; kv0 += KVB) {
    {
      const short* kp = kb + base + (size_t)(kv0 + kr) * Dh + kc;
      bfx8 u0 = *(const bfx8*)kp;
      bfx8 u1 = *(const bfx8*)(kp + 8);
      *(bfx8*)&Ks[kr * LDK + kc] = u0;
      *(bfx8*)&Ks[kr * LDK + kc + 8] = u1;
    }
    {
      const short* vp = vb + base + (size_t)kr * Sq + kv0 + kc;
      bfx8 u0 = *(const bfx8*)vp;
      bfx8 u1 = *(const bfx8*)(vp + 8);
      *(bfx8*)&Vt[kr * LDK + kc] = u0;
      *(bfx8*)&Vt[kr * LDK + kc + 8] = u1;
    }
    __syncthreads();

    fx4 sa[4] = {};
#pragma unroll
    for (int nf = 0; nf < 4; ++nf) {
#pragma unroll
      for (int ks = 0; ks < 2; ++ks) {
        bfx8 kf = *(const bfx8*)&Ks[(nf * 16 + fr) * LDK + ks * 32 + fq * 8];
        sa[nf] = __builtin_amdgcn_mfma_f32_16x16x32_bf16(qf[ks], kf, sa[nf], 0, 0, 0);
      }
    }

#pragma unroll
    for (int i = 0; i < 4; ++i) {
      float mx = fmaxf(fmaxf(sa[0][i], sa[1][i]), fmaxf(sa[2][i], sa[3][i]));
      mx = fmaxf(mx, __shfl_xor(mx, 1));
      mx = fmaxf(mx, __shfl_xor(mx, 2));
      mx = fmaxf(mx, __shfl_xor(mx, 4));
      mx = fmaxf(mx, __shfl_xor(mx, 8));
      mx *= 0.125f;
      const float mn = fmaxf(mrow[i], mx);
      const float alpha = __expf(mrow[i] - mn);
      mrow[i] = mn;
      float rs = 0.f;
#pragma unroll
      for (int nf = 0; nf < 4; ++nf) {
        const float p = __expf(sa[nf][i] * 0.125f - mn);
        rs += p;
        Ps[wave][(fq * 4 + i) * LDK + nf * 16 + fr] = f2bf(p);
      }
      rs += __shfl_xor(rs, 1);
      rs += __shfl_xor(rs, 2);
      rs += __shfl_xor(rs, 4);
      rs += __shfl_xor(rs, 8);
      lrow[i] = lrow[i] * alpha + rs;
#pragma unroll
      for (int df = 0; df < 4; ++df) oacc[df][i] *= alpha;
    }
    __syncthreads();

    bfx8 pf[2];
    pf[0] = *(const bfx8*)&Ps[wave][fr * LDK + fq * 8];
    pf[1] = *(const bfx8*)&Ps[wave][fr * LDK + 32 + fq * 8];
#pragma unroll
    for (int df = 0; df < 4; ++df) {
#pragma unroll
      for (int ks = 0; ks < 2; ++ks) {
        bfx8 vf = *(const bfx8*)&Vt[(df * 16 + fr) * LDK + ks * 32 + fq * 8];
        oacc[df] = __builtin_amdgcn_mfma_f32_16x16x32_bf16(pf[ks], vf, oacc[df], 0, 0, 0);
      }
    }
    __syncthreads();
  }

  const int b = bh >> 4, h = bh & 15;
#pragma unroll
  for (int df = 0; df < 4; ++df) {
    const int d = df * 16 + fr;
#pragma unroll
    for (int i = 0; i < 4; ++i) {
      const int qrow = q0 + fq * 4 + i;
      const float o = oacc[df][i] / lrow[i];
      wv[((size_t)b * Sq + qrow) * Em + h * Dh + d] = f2bf(o);
    }
  }
}

extern "C" void kernel_launch(void* const* d_in, const int* in_sizes, int n_in,
                              void* d_out, int out_size, void* d_ws, size_t ws_size,
                              hipStream_t stream) {
  (void)in_sizes; (void)n_in; (void)out_size; (void)ws_size;
  const float* query = (const float*)d_in[0];
  const float* key   = (const float*)d_in[1];
  const float* value = (const float*)d_in[2];
  const float* Wq = (const float*)d_in[3];
  const float* bq = (const float*)d_in[4];
  const float* Wk = (const float*)d_in[5];
  const float* bk = (const float*)d_in[6];
  const float* Wv = (const float*)d_in[7];
  const float* bv = (const float*)d_in[8];
  const float* Wo = (const float*)d_in[9];
  const float* bo = (const float*)d_in[10];
  const float* pos = (const float*)d_in[11];

  short* qx = (short*)d_ws;
  short* kx = qx + NE;
  short* vx = kx + NE;
  short* Wqb = vx + NE;
  short* Wkb = Wqb + WE;
  short* Wvb = Wkb + WE;
  short* Wob = Wvb + WE;
  short* qb = Wob + WE;
  short* wv = qx;                 // alias: qx dead after gemm_qkv
  short* kb = (short*)d_out;      // d_out scratch, overwritten by gemm_out
  short* vb = kb + NE;            // [B,H,Dh,S]

  convert_kernel<<<dim3(8192), 256, 0, stream>>>(
      query, key, value, Wq, Wk, Wv, Wo, qx, kx, vx, Wqb, Wkb, Wvb, Wob);
  gemm_qkv_bf16<<<dim3(Mrows / 128, Em / 128, 3), 256, 0, stream>>>(
      qx, kx, vx, Wqb, Wkb, Wvb, bq, bk, bv, pos, qb, kb, vb);
  attn_kernel<<<dim3(Bz * Hn, Sq / 64), 256, 0, stream>>>(qb, kb, vb, wv);
  gemm_out_bf16<<<dim3(Mrows / 128, Em / 128), 256, 0, stream>>>(
      wv, Wob, bo, (float*)d_out);
}

// Round 7
// 116.436 us; speedup vs baseline: 1.1455x; 1.1455x over previous
//
#include <hip/hip_runtime.h>
#include <hip/hip_bf16.h>

typedef __attribute__((ext_vector_type(8))) short bfx8;
typedef __attribute__((ext_vector_type(4))) short bfx4;
typedef __attribute__((ext_vector_type(4))) float fx4;

static __device__ __forceinline__ short f2bf(float f) {
  union { float f; unsigned u; } v; v.f = f;
  unsigned r = v.u + 0x7fffu + ((v.u >> 16) & 1u);
  return (short)(r >> 16);
}

static __device__ __forceinline__ void gld16(const void* g, void* l) {
  __builtin_amdgcn_global_load_lds(
      (const __attribute__((address_space(1))) void*)g,
      (__attribute__((address_space(3))) void*)l, 16, 0, 0);
}

constexpr int Bz = 8, Sq = 512, Em = 1024, Hn = 16, Dh = 64;
constexpr int Mrows = Bz * Sq;             // 4096
constexpr size_t NE = (size_t)Mrows * Em;  // 4,194,304
constexpr size_t WE = (size_t)Em * Em;     // 1,048,576

// ---------------- f32 -> bf16 pre-convert (memory-bound, exact flat grid) ----------------
__global__ __launch_bounds__(256) void convert_kernel(
    const float* __restrict__ q, const float* __restrict__ k,
    const float* __restrict__ v,
    const float* __restrict__ Wq, const float* __restrict__ Wk,
    const float* __restrict__ Wv, const float* __restrict__ Wo,
    short* __restrict__ qx, short* __restrict__ kx, short* __restrict__ vx,
    short* __restrict__ wqb, short* __restrict__ wkb,
    short* __restrict__ wvb, short* __restrict__ wob)
{
  const size_t c = (size_t)blockIdx.x * 256 + threadIdx.x;  // vec8 chunk id
  constexpr size_t CI = NE / 8;   // 524288
  constexpr size_t CW = WE / 8;   // 131072
  const float* src; short* dst; size_t off;
  if (c < 3 * CI) {
    const int sgi = (int)(c / CI);
    src = sgi == 0 ? q : sgi == 1 ? k : v;
    dst = sgi == 0 ? qx : sgi == 1 ? kx : vx;
    off = (c - (size_t)sgi * CI) * 8;
  } else {
    const size_t w = c - 3 * CI;
    const int sgi = (int)(w / CW);
    src = sgi == 0 ? Wq : sgi == 1 ? Wk : sgi == 2 ? Wv : Wo;
    dst = sgi == 0 ? wqb : sgi == 1 ? wkb : sgi == 2 ? wvb : wob;
    off = (w - (size_t)sgi * CW) * 8;
  }
  fx4 a = *(const fx4*)(src + off);
  fx4 b = *(const fx4*)(src + off + 4);
  bfx8 o = { f2bf(a[0]), f2bf(a[1]), f2bf(a[2]), f2bf(a[3]),
             f2bf(b[0]), f2bf(b[1]), f2bf(b[2]), f2bf(b[3]) };
  *(bfx8*)(dst + off) = o;
}

// ---------------- bf16 GEMM, C^T orientation, BK=64 single-buffered ----------------
// LDS: As/Bs = [128][64] bf16 (16KB each, 32KB staging); epilogue reuses SM as
// 128x136 C-tile (34.8KB union -> 4 blocks/CU). 16 K-steps, 2 barriers each.
// XOR swizzle (both-sides): gload_lds writes linear; SOURCE col pre-swizzled
// ((t&7)^(row&7)), ds_read uses chunk j^(row&7) -> conflict-free b128 reads.
constexpr int LDP = 136;

__global__ __launch_bounds__(256, 4) void gemm_qkv_bf16(
    const short* __restrict__ qx, const short* __restrict__ kx,
    const short* __restrict__ vx,
    const short* __restrict__ Wqb, const short* __restrict__ Wkb,
    const short* __restrict__ Wvb,
    const float* __restrict__ bq, const float* __restrict__ bk,
    const float* __restrict__ bv,
    const float* __restrict__ pos,
    short* __restrict__ qb, short* __restrict__ kb, short* __restrict__ vb)
{
  __shared__ short SM[128 * LDP];
  short* As = SM;            // [128][64]
  short* Bs = SM + 8192;     // [128][64]

  const int z = blockIdx.z;
  const short* X = (z == 0) ? qx : (z == 1) ? kx : vx;
  const short* W = (z == 0) ? Wqb : (z == 1) ? Wkb : Wvb;
  const float* bias = (z == 0) ? bq : (z == 1) ? bk : bv;
  short* dst = (z == 0) ? qb : (z == 1) ? kb : vb;

  const int m0 = blockIdx.x * 128;   // over Mrows (fast axis -> XCD locality)
  const int n0 = blockIdx.y * 128;   // over Em
  const int t = threadIdx.x, lane = t & 63, wave = t >> 6;
  const int wr = wave >> 1, wc = wave & 1;
  const int fr = lane & 15, fq = lane >> 4;

  // staging: round r, thread t -> row 32r+(t>>3), LDS chunk 256r+t (linear),
  // source col chunk (t&7)^(row&7)  [involution with the read-side XOR]
  const int trow = t >> 3;
  const int scol = ((t & 7) ^ (trow & 7)) * 8;
  const short* gW = W + (size_t)(n0 + trow) * Em + scol;
  const short* gX = X + (size_t)(m0 + trow) * Em + scol;
  short* lA = As + wave * 512;   // + r*2048
  short* lB = Bs + wave * 512;

  // read-side swizzled chunk offsets (elems): half ks, col-chunk (ks*4+fq)^(fr&7)
  const int sw0 = ((fq ^ (fr & 7)) * 8);
  const int sw1 = (((4 + fq) ^ (fr & 7)) * 8);

  fx4 acc[4][4] = {};

  for (int k0 = 0; k0 < Em; k0 += 64) {
#pragma unroll
    for (int r = 0; r < 4; ++r) {
      gld16(gW + (size_t)(32 * r) * Em + k0, lA + r * 2048);
      gld16(gX + (size_t)(32 * r) * Em + k0, lB + r * 2048);
    }
    __syncthreads();

#pragma unroll
    for (int ks = 0; ks < 2; ++ks) {
      const int sw = ks ? sw1 : sw0;
      bfx8 af[4], bf[4];
#pragma unroll
      for (int u = 0; u < 4; ++u)
        af[u] = *(const bfx8*)&As[(wr * 64 + u * 16 + fr) * 64 + sw];
#pragma unroll
      for (int v = 0; v < 4; ++v)
        bf[v] = *(const bfx8*)&Bs[(wc * 64 + v * 16 + fr) * 64 + sw];
#pragma unroll
      for (int u = 0; u < 4; ++u)
#pragma unroll
        for (int v = 0; v < 4; ++v)
          acc[u][v] = __builtin_amdgcn_mfma_f32_16x16x32_bf16(af[u], bf[v], acc[u][v], 0, 0, 0);
    }
    __syncthreads();
  }

  // ---- epilogue: +bias+pe, bounce through LDS, coalesced bfx8 stores ----
  const int rr = t >> 4, jj = t & 15;
  const int b = m0 >> 9;
  if (z < 2) {
    // C-tile [m][nn], readback rows m -> [B,H,S,Dh] (contiguous d)
#pragma unroll
    for (int u = 0; u < 4; ++u) {
      const int nn = wr * 64 + u * 16 + fq * 4;
      const int nng = n0 + nn;
      const fx4 bb = *(const fx4*)&bias[nng];
#pragma unroll
      for (int v = 0; v < 4; ++v) {
        const int m = wc * 64 + v * 16 + fr;
        const int s = (m0 + m) & (Sq - 1);
        const fx4 pe = *(const fx4*)&pos[(size_t)s * Em + nng];
        const fx4 a = acc[u][v];
        bfx4 o = { f2bf(a[0] + bb[0] + pe[0]), f2bf(a[1] + bb[1] + pe[1]),
                   f2bf(a[2] + bb[2] + pe[2]), f2bf(a[3] + bb[3] + pe[3]) };
        *(bfx4*)&SM[m * LDP + nn] = o;
      }
    }
    __syncthreads();
#pragma unroll
    for (int it = 0; it < 8; ++it) {
      const int m = it * 16 + rr;
      const int s = (m0 + m) & (Sq - 1);
      bfx8 val = *(const bfx8*)&SM[m * LDP + jj * 8];
      const int nng = n0 + jj * 8;
      const int h = nng >> 6, d = nng & 63;
      *(bfx8*)&dst[(((size_t)b * Hn + h) * Sq + s) * Dh + d] = val;
    }
  } else {
    // C-tile [nn][m^swz]; readback rows nn -> V^T [B,H,Dh,S] (contiguous s)
#pragma unroll
    for (int u = 0; u < 4; ++u) {
      const int nnb = wr * 64 + u * 16 + fq * 4;
      const int nng = n0 + nnb;
      const fx4 bb = *(const fx4*)&bias[nng];
#pragma unroll
      for (int v = 0; v < 4; ++v) {
        const int m = wc * 64 + v * 16 + fr;
        const int s = (m0 + m) & (Sq - 1);
        const fx4 pe = *(const fx4*)&pos[(size_t)s * Em + nng];
        const fx4 a = acc[u][v];
#pragma unroll
        for (int i = 0; i < 4; ++i) {
          const int row = nnb + i;
          SM[row * LDP + (m ^ ((row & 12) << 2))] = f2bf(a[i] + bb[i] + pe[i]);
        }
      }
    }
    __syncthreads();
    const int s0 = m0 & (Sq - 1);
#pragma unroll
    for (int it = 0; it < 8; ++it) {
      const int row = it * 16 + rr;
      bfx8 val = *(const bfx8*)&SM[row * LDP + ((jj * 8) ^ ((row & 12) << 2))];
      const int nng = n0 + row;
      const int h = nng >> 6, d = nng & 63;
      *(bfx8*)&dst[(((size_t)b * Hn + h) * Dh + d) * Sq + s0 + jj * 8] = val;
    }
  }
}

// output projection: out = wv @ Wo^T + bo  (f32 out, vector stores)
__global__ __launch_bounds__(256, 4) void gemm_out_bf16(
    const short* __restrict__ wv, const short* __restrict__ Wob,
    const float* __restrict__ bo, float* __restrict__ out)
{
  __shared__ short SM[2 * 8192];
  short* As = SM;
  short* Bs = SM + 8192;

  const int m0 = blockIdx.x * 128;
  const int n0 = blockIdx.y * 128;
  const int t = threadIdx.x, lane = t & 63, wave = t >> 6;
  const int wr = wave >> 1, wc = wave & 1;
  const int fr = lane & 15, fq = lane >> 4;

  const int trow = t >> 3;
  const int scol = ((t & 7) ^ (trow & 7)) * 8;
  const short* gW = Wob + (size_t)(n0 + trow) * Em + scol;
  const short* gX = wv + (size_t)(m0 + trow) * Em + scol;
  short* lA = As + wave * 512;
  short* lB = Bs + wave * 512;

  const int sw0 = ((fq ^ (fr & 7)) * 8);
  const int sw1 = (((4 + fq) ^ (fr & 7)) * 8);

  fx4 acc[4][4] = {};

  for (int k0 = 0; k0 < Em; k0 += 64) {
#pragma unroll
    for (int r = 0; r < 4; ++r) {
      gld16(gW + (size_t)(32 * r) * Em + k0, lA + r * 2048);
      gld16(gX + (size_t)(32 * r) * Em + k0, lB + r * 2048);
    }
    __syncthreads();

#pragma unroll
    for (int ks = 0; ks < 2; ++ks) {
      const int sw = ks ? sw1 : sw0;
      bfx8 af[4], bf[4];
#pragma unroll
      for (int u = 0; u < 4; ++u)
        af[u] = *(const bfx8*)&As[(wr * 64 + u * 16 + fr) * 64 + sw];
#pragma unroll
      for (int v = 0; v < 4; ++v)
        bf[v] = *(const bfx8*)&Bs[(wc * 64 + v * 16 + fr) * 64 + sw];
#pragma unroll
      for (int u = 0; u < 4; ++u)
#pragma unroll
        for (int v = 0; v < 4; ++v)
          acc[u][v] = __builtin_amdgcn_mfma_f32_16x16x32_bf16(af[u], bf[v], acc[u][v], 0, 0, 0);
    }
    __syncthreads();
  }

#pragma unroll
  for (int u = 0; u < 4; ++u) {
    const int nn = n0 + wr * 64 + u * 16 + fq * 4;
    const fx4 bb = *(const fx4*)&bo[nn];
#pragma unroll
    for (int v = 0; v < 4; ++v) {
      const int m = m0 + wc * 64 + v * 16 + fr;
      fx4 val = acc[u][v];
      val[0] += bb[0]; val[1] += bb[1]; val[2] += bb[2]; val[3] += bb[3];
      *(fx4*)&out[(size_t)m * Em + nn] = val;
    }
  }
}

// ---------------- Attention (unchanged from R5) ----------------
constexpr int KVB = 64, LDK = 72;

__global__ __launch_bounds__(256) void attn_kernel(
    const short* __restrict__ qb, const short* __restrict__ kb,
    const short* __restrict__ vb, short* __restrict__ wv)
{
  __shared__ short Ks[KVB * LDK];
  __shared__ short Vt[Dh * LDK];
  __shared__ short Ps[4][16 * LDK];

  const int bh = blockIdx.x;
  const int qt = blockIdx.y;
  const int t = threadIdx.x, lane = t & 63, wave = t >> 6;
  const int fr = lane & 15, fq = lane >> 4;

  const size_t base = (size_t)bh * Sq * Dh;
  const int q0 = qt * 64 + wave * 16;

  bfx8 qf[2];
  {
    const short* qp = qb + base + (size_t)(q0 + fr) * Dh;
    qf[0] = *(const bfx8*)(qp + fq * 8);
    qf[1] = *(const bfx8*)(qp + 32 + fq * 8);
  }

  float mrow[4] = { -1e30f, -1e30f, -1e30f, -1e30f };
  float lrow[4] = { 0.f, 0.f, 0.f, 0.f };
  fx4 oacc[4] = {};

  const int kr = t >> 2, kc = (t & 3) * 16;

  for (int kv0 = 0; kv0 < Sq; kv0 += KVB) {
    {
      const short* kp = kb + base + (size_t)(kv0 + kr) * Dh + kc;
      bfx8 u0 = *(const bfx8*)kp;
      bfx8 u1 = *(const bfx8*)(kp + 8);
      *(bfx8*)&Ks[kr * LDK + kc] = u0;
      *(bfx8*)&Ks[kr * LDK + kc + 8] = u1;
    }
    {
      const short* vp = vb + base + (size_t)kr * Sq + kv0 + kc;
      bfx8 u0 = *(const bfx8*)vp;
      bfx8 u1 = *(const bfx8*)(vp + 8);
      *(bfx8*)&Vt[kr * LDK + kc] = u0;
      *(bfx8*)&Vt[kr * LDK + kc + 8] = u1;
    }
    __syncthreads();

    fx4 sa[4] = {};
#pragma unroll
    for (int nf = 0; nf < 4; ++nf) {
#pragma unroll
      for (int ks = 0; ks < 2; ++ks) {
        bfx8 kf = *(const bfx8*)&Ks[(nf * 16 + fr) * LDK + ks * 32 + fq * 8];
        sa[nf] = __builtin_amdgcn_mfma_f32_16x16x32_bf16(qf[ks], kf, sa[nf], 0, 0, 0);
      }
    }

#pragma unroll
    for (int i = 0; i < 4; ++i) {
      float mx = fmaxf(fmaxf(sa[0][i], sa[1][i]), fmaxf(sa[2][i], sa[3][i]));
      mx = fmaxf(mx, __shfl_xor(mx, 1));
      mx = fmaxf(mx, __shfl_xor(mx, 2));
      mx = fmaxf(mx, __shfl_xor(mx, 4));
      mx = fmaxf(mx, __shfl_xor(mx, 8));
      mx *= 0.125f;
      const float mn = fmaxf(mrow[i], mx);
      const float alpha = __expf(mrow[i] - mn);
      mrow[i] = mn;
      float rs = 0.f;
#pragma unroll
      for (int nf = 0; nf < 4; ++nf) {
        const float p = __expf(sa[nf][i] * 0.125f - mn);
        rs += p;
        Ps[wave][(fq * 4 + i) * LDK + nf * 16 + fr] = f2bf(p);
      }
      rs += __shfl_xor(rs, 1);
      rs += __shfl_xor(rs, 2);
      rs += __shfl_xor(rs, 4);
      rs += __shfl_xor(rs, 8);
      lrow[i] = lrow[i] * alpha + rs;
#pragma unroll
      for (int df = 0; df < 4; ++df) oacc[df][i] *= alpha;
    }
    __syncthreads();

    bfx8 pf[2];
    pf[0] = *(const bfx8*)&Ps[wave][fr * LDK + fq * 8];
    pf[1] = *(const bfx8*)&Ps[wave][fr * LDK + 32 + fq * 8];
#pragma unroll
    for (int df = 0; df < 4; ++df) {
#pragma unroll
      for (int ks = 0; ks < 2; ++ks) {
        bfx8 vf = *(const bfx8*)&Vt[(df * 16 + fr) * LDK + ks * 32 + fq * 8];
        oacc[df] = __builtin_amdgcn_mfma_f32_16x16x32_bf16(pf[ks], vf, oacc[df], 0, 0, 0);
      }
    }
    __syncthreads();
  }

  const int b = bh >> 4, h = bh & 15;
#pragma unroll
  for (int df = 0; df < 4; ++df) {
    const int d = df * 16 + fr;
#pragma unroll
    for (int i = 0; i < 4; ++i) {
      const int qrow = q0 + fq * 4 + i;
      const float o = oacc[df][i] / lrow[i];
      wv[((size_t)b * Sq + qrow) * Em + h * Dh + d] = f2bf(o);
    }
  }
}

extern "C" void kernel_launch(void* const* d_in, const int* in_sizes, int n_in,
                              void* d_out, int out_size, void* d_ws, size_t ws_size,
                              hipStream_t stream) {
  (void)in_sizes; (void)n_in; (void)out_size; (void)ws_size;
  const float* query = (const float*)d_in[0];
  const float* key   = (const float*)d_in[1];
  const float* value = (const float*)d_in[2];
  const float* Wq = (const float*)d_in[3];
  const float* bq = (const float*)d_in[4];
  const float* Wk = (const float*)d_in[5];
  const float* bk = (const float*)d_in[6];
  const float* Wv = (const float*)d_in[7];
  const float* bv = (const float*)d_in[8];
  const float* Wo = (const float*)d_in[9];
  const float* bo = (const float*)d_in[10];
  const float* pos = (const float*)d_in[11];

  short* qx = (short*)d_ws;
  short* kx = qx + NE;
  short* vx = kx + NE;
  short* Wqb = vx + NE;
  short* Wkb = Wqb + WE;
  short* Wvb = Wkb + WE;
  short* Wob = Wvb + WE;
  short* qb = Wob + WE;
  short* wv = qx;                 // alias: qx dead after gemm_qkv
  short* kb = (short*)d_out;      // d_out scratch, overwritten by gemm_out
  short* vb = kb + NE;            // [B,H,Dh,S]

  convert_kernel<<<dim3(8192), 256, 0, stream>>>(
      query, key, value, Wq, Wk, Wv, Wo, qx, kx, vx, Wqb, Wkb, Wvb, Wob);
  gemm_qkv_bf16<<<dim3(Mrows / 128, Em / 128, 3), 256, 0, stream>>>(
      qx, kx, vx, Wqb, Wkb, Wvb, bq, bk, bv, pos, qb, kb, vb);
  attn_kernel<<<dim3(Bz * Hn, Sq / 64), 256, 0, stream>>>(qb, kb, vb, wv);
  gemm_out_bf16<<<dim3(Mrows / 128, Em / 128), 256, 0, stream>>>(
      wv, Wob, bo, (float*)d_out);
}